// Round 1
// baseline (160.150 us; speedup 1.0000x reference)
//
#include <hip/hip_runtime.h>
#include <math.h>

// Problem sizes (fixed by setup_inputs)
constexpr int BATCH = 64;
constexpr int IN    = 1024;
constexpr int NN    = 2048;   // num_neurons
constexpr int OUTF  = 1024;

constexpr float SCALE   = 651.8986469044033f;   // 4096 / (2*pi)
constexpr float INV4096 = 2.44140625e-4f;       // 1/4096
constexpr float SQRT2   = 1.4142135623730951f;

// Kernel-1 tiling
constexpr int KSPLIT = 2;              // k-slabs -> 2 partial buffers
constexpr int KRANGE = IN / KSPLIT;    // 512 k per block
constexpr int KC     = 256;            // staged k-chunk
constexpr int PAD    = 260;            // LDS row stride in floats (16B aligned, odd*4 -> conflict-free)

// interference partials: part[kslab][n][b], kslab in {0,1}
// ws usage: 2*2048*64*4 = 1 MiB

__global__ __launch_bounds__(256, 4)
void k_interf(const float* __restrict__ x, const float* __restrict__ W,
              const float* __restrict__ B, float* __restrict__ part) {
    __shared__ float xs[32 * PAD];   // 32 batches x 256 k (padded) = 33.3 KB

    const int tid   = threadIdx.x;
    const int lane  = tid & 63;
    const int wv    = tid >> 6;                 // 0..3 : wave id -> neuron within group
    const int bid   = blockIdx.x;               // 1024 blocks
    const int kslab = bid & (KSPLIT - 1);
    const int ngrp  = bid >> 1;                 // 0..511
    const int n     = ngrp * 4 + wv;            // neuron handled by this wave
    const int k0    = kslab * KRANGE;

    float acc[BATCH];
#pragma unroll
    for (int b = 0; b < BATCH; ++b) acc[b] = 0.0f;

    for (int kc = 0; kc < KRANGE; kc += KC) {
        const int kb = k0 + kc;

        // per-lane prep for 4 k values: inv = SCALE/(1+|W|), bsc = B*SCALE
        const float4 w4 = *(const float4*)&W[(size_t)n * IN + kb + 4 * lane];
        const float4 b4 = *(const float4*)&B[(size_t)n * IN + kb + 4 * lane];
        float4 inv, bsc;
        inv.x = SCALE * __builtin_amdgcn_rcpf(1.0f + fabsf(w4.x));
        inv.y = SCALE * __builtin_amdgcn_rcpf(1.0f + fabsf(w4.y));
        inv.z = SCALE * __builtin_amdgcn_rcpf(1.0f + fabsf(w4.z));
        inv.w = SCALE * __builtin_amdgcn_rcpf(1.0f + fabsf(w4.w));
        bsc.x = b4.x * SCALE;
        bsc.y = b4.y * SCALE;
        bsc.z = b4.z * SCALE;
        bsc.w = b4.w * SCALE;

#pragma unroll
        for (int h = 0; h < 2; ++h) {           // batch halves: rows h*32 .. h*32+31
            __syncthreads();
            // stage x[h*32 .. h*32+31][kb .. kb+255] into LDS (coalesced f4, conflict-free writes)
            {
                const int r  = tid >> 5;          // 0..7
                const int c  = (tid & 31) * 4;    // 0..124
                const float* gx = x + (size_t)(h * 32) * IN + kb;
#pragma unroll
                for (int rr = 0; rr < 32; rr += 8) {
#pragma unroll
                    for (int ch = 0; ch < 2; ++ch) {
                        const float4 v = *(const float4*)&gx[(size_t)(r + rr) * IN + ch * 128 + c];
                        *(float4*)&xs[(r + rr) * PAD + ch * 128 + c] = v;
                    }
                }
            }
            __syncthreads();

#pragma unroll
            for (int bb = 0; bb < 32; ++bb) {
                const float4 xv = *(const float4*)&xs[bb * PAD + 4 * lane];
                // s = theta*SCALE ; quantized angle in revolutions = rint(s)/4096 ; +1/8 rev = +pi/4
                const float s0 = fmaf(xv.x, inv.x, bsc.x);
                const float s1 = fmaf(xv.y, inv.y, bsc.y);
                const float s2 = fmaf(xv.z, inv.z, bsc.z);
                const float s3 = fmaf(xv.w, inv.w, bsc.w);
                const float a0 = fmaf(__builtin_rintf(s0), INV4096, 0.125f);
                const float a1 = fmaf(__builtin_rintf(s1), INV4096, 0.125f);
                const float a2 = fmaf(__builtin_rintf(s2), INV4096, 0.125f);
                const float a3 = fmaf(__builtin_rintf(s3), INV4096, 0.125f);
                const float t0 = __builtin_amdgcn_sinf(a0);  // sin(2*pi*a)
                const float t1 = __builtin_amdgcn_sinf(a1);
                const float t2 = __builtin_amdgcn_sinf(a2);
                const float t3 = __builtin_amdgcn_sinf(a3);
                acc[h * 32 + bb] += (t0 + t1) + (t2 + t3);
            }
        }
    }

    // cross-lane transpose-reduction: after this, lane l holds the full sum for batch b=l
#pragma unroll
    for (int m = 32; m >= 1; m >>= 1) {
        const bool hi = (lane & m) != 0;
#pragma unroll
        for (int j = 0; j < m; ++j) {
            const float send = hi ? acc[j] : acc[j + m];
            const float recv = __shfl_xor(send, m, 64);
            acc[j] = (hi ? acc[j + m] : acc[j]) + recv;
        }
    }

    part[((size_t)kslab * NN + n) * 64 + lane] = acc[0] * SQRT2;
}

// Stage 2: out[b][o] = sum_n (p0[n][b]+p1[n][b]) * out_w[o][n]
// grid = 64 o-tiles (16 wide) x 8 n-splits = 512 blocks; atomicAdd into zeroed d_out
constexpr int NSPLIT = 8;
constexpr int NRANGE = NN / NSPLIT;   // 256

__global__ __launch_bounds__(256)
void k_proj(const float* __restrict__ part, const float* __restrict__ ow,
            float* __restrict__ out) {
    const int tid  = threadIdx.x;
    const int lane = tid & 63;                       // = batch b
    const int og   = __builtin_amdgcn_readfirstlane(tid >> 6);  // 0..3, wave-uniform
    const int bid  = blockIdx.x;
    const int ot   = bid >> 3;                       // 0..63
    const int ns   = bid & 7;
    const int o0   = ot * 16 + og * 4;

    const float* p0 = part;
    const float* p1 = part + (size_t)NN * 64;

    float a0 = 0.f, a1 = 0.f, a2 = 0.f, a3 = 0.f;
    const int nbeg = ns * NRANGE;
#pragma unroll 4
    for (int n = nbeg; n < nbeg + NRANGE; ++n) {
        const float v = p0[(size_t)n * 64 + lane] + p1[(size_t)n * 64 + lane];
        a0 = fmaf(v, ow[(size_t)(o0 + 0) * NN + n], a0);
        a1 = fmaf(v, ow[(size_t)(o0 + 1) * NN + n], a1);
        a2 = fmaf(v, ow[(size_t)(o0 + 2) * NN + n], a2);
        a3 = fmaf(v, ow[(size_t)(o0 + 3) * NN + n], a3);
    }
    atomicAdd(&out[(size_t)lane * OUTF + o0 + 0], a0);
    atomicAdd(&out[(size_t)lane * OUTF + o0 + 1], a1);
    atomicAdd(&out[(size_t)lane * OUTF + o0 + 2], a2);
    atomicAdd(&out[(size_t)lane * OUTF + o0 + 3], a3);
}

extern "C" void kernel_launch(void* const* d_in, const int* in_sizes, int n_in,
                              void* d_out, int out_size, void* d_ws, size_t ws_size,
                              hipStream_t stream) {
    const float* x  = (const float*)d_in[0];
    const float* W  = (const float*)d_in[1];
    const float* B  = (const float*)d_in[2];
    const float* ow = (const float*)d_in[3];
    // d_in[4], d_in[5]: sin/cos tables — replaced by exact hw-sin identity
    float* out  = (float*)d_out;
    float* part = (float*)d_ws;   // 2 * 2048 * 64 floats = 1 MiB

    hipMemsetAsync(d_out, 0, (size_t)out_size * sizeof(float), stream);
    k_interf<<<dim3(512 * KSPLIT), dim3(256), 0, stream>>>(x, W, B, part);
    k_proj<<<dim3(64 * NSPLIT), dim3(256), 0, stream>>>(part, ow, out);
}